// Round 1
// baseline (286.404 us; speedup 1.0000x reference)
//
#include <hip/hip_runtime.h>
#include <math.h>

// Output: adj (M x M float32), M = N + 4.
//   adj[i][i] = 1.0  for i < N
//   adj[i][j] = 0.25 for i,j >= N   (includes those diagonal entries)
//   else 0.
// Strategy: hipMemsetAsync the whole output to 0 (near-peak store BW),
// then a tiny fixup kernel writes the ~M nonzero entries.

__global__ void ADJ_fixup_kernel(float* __restrict__ out, int N, int M) {
    int i = blockIdx.x * blockDim.x + threadIdx.x;
    if (i < N) {
        // diagonal entry, degree-1 node: d_i * 1 * d_i = 1.0
        out[(size_t)i * (size_t)M + (size_t)i] = 1.0f;
    } else if (i < M) {
        // bottom 4 rows: columns N..M-1 are all 0.25 (d=0.5 both sides, A=1)
        size_t row_base = (size_t)i * (size_t)M;
        #pragma unroll
        for (int j = 0; j < 4; ++j) {
            out[row_base + (size_t)(N + j)] = 0.25f;
        }
    }
}

extern "C" void kernel_launch(void* const* d_in, const int* in_sizes, int n_in,
                              void* d_out, int out_size, void* d_ws, size_t ws_size,
                              hipStream_t stream) {
    (void)d_in; (void)in_sizes; (void)n_in; (void)d_ws; (void)ws_size;

    // M is the output's square dimension; derive from out_size (M*M elements).
    int M = (int)(sqrt((double)out_size) + 0.5);
    int N = M - 4;

    float* out = (float*)d_out;

    // Zero the whole output (graph-capturable async memset).
    hipMemsetAsync(d_out, 0, (size_t)out_size * sizeof(float), stream);

    // Write the nonzero entries: M threads, one per row.
    int block = 256;
    int grid = (M + block - 1) / block;
    ADJ_fixup_kernel<<<grid, block, 0, stream>>>(out, N, M);
}